// Round 5
// baseline (711.937 us; speedup 1.0000x reference)
//
#include <hip/hip_runtime.h>
#include <hip/hip_bf16.h>
#include <stdint.h>

typedef unsigned short u16;
typedef __bf16 bf16x8 __attribute__((ext_vector_type(8)));
typedef float f32x4 __attribute__((ext_vector_type(4)));
typedef u16 u16x8 __attribute__((ext_vector_type(8)));

#define MFMA16(a, b, c) __builtin_amdgcn_mfma_f32_16x16x32_bf16(a, b, c, 0, 0, 0)

typedef __attribute__((address_space(3))) unsigned as3_uint;
typedef __attribute__((address_space(1))) unsigned as1_uint;

__device__ __forceinline__ void gload_lds16(const void* g, void* l) {
  __builtin_amdgcn_global_load_lds((const as1_uint*)g, (as3_uint*)l, 16, 0, 0);
}

__device__ __forceinline__ u16 f2bf(float f) {
  unsigned u = __float_as_uint(f);
  u += 0x7FFF + ((u >> 16) & 1);
  return (u16)(u >> 16);
}

// y = b[i]*clamp(x) + c[i], uniform grid
__device__ __forceinline__ float pwl_lin(float x, float x0, float x1, float invStep,
                                         const float* __restrict__ Bt,
                                         const float* __restrict__ Ct) {
  float xc = fminf(fmaxf(x, x0), x1);
  int i = (int)floorf((x - x0) * invStep);
  i = max(0, min(510, i));
  return fmaf(Bt[i], xc, Ct[i]);
}

// geometric grid: index via log
__device__ __forceinline__ float pwl_log(float x, float x0, float x1, float lnx0, float invL,
                                         const float* __restrict__ Bt,
                                         const float* __restrict__ Ct) {
  float xc = fminf(fmaxf(x, x0), x1);
  int i = (int)floorf((logf(xc) - lnx0) * invL);
  i = max(0, min(510, i));
  return fmaf(Bt[i], xc, Ct[i]);
}

// ---- table init: (b,c) per segment for gelu/exp/inv/rsqrt, numpy-matched ----
__global__ void init_tables(float* __restrict__ tb) {
  __shared__ float xs[4][512], ys[4][512];
  int i = threadIdx.x;
  if (i < 512) {
    double t = (double)i / 511.0;
    float xg = (float)(-10.0 + 20.0 * t);
    double xd = (double)xg;
    xs[0][i] = xg;
    ys[0][i] = (float)(0.5 * xd * (1.0 + tanh(0.7978845608028654 * (xd + 0.044715 * xd * xd * xd))));
    float xe = (float)(-30.0 + 30.0 * t);
    xs[1][i] = xe;
    ys[1][i] = (float)exp((double)xe);
    double li = -3.0 + t * (log10(4096.0) + 3.0);
    float xi = (float)pow(10.0, li);
    if (i == 0) xi = 1e-3f;
    if (i == 511) xi = 4096.0f;
    xs[2][i] = xi;
    ys[2][i] = 1.0f / xi;
    double lr = -6.0 + t * 8.0;
    float xr2 = (float)pow(10.0, lr);
    if (i == 0) xr2 = 1e-6f;
    if (i == 511) xr2 = 100.0f;
    xs[3][i] = xr2;
    ys[3][i] = 1.0f / sqrtf(xr2);
  }
  __syncthreads();
  if (i < 511) {
#pragma unroll
    for (int tc = 0; tc < 4; ++tc) {
      double bq = ((double)ys[tc][i + 1] - (double)ys[tc][i]) /
                  ((double)xs[tc][i + 1] - (double)xs[tc][i]);
      double cq = (double)ys[tc][i] - bq * (double)xs[tc][i];
      tb[tc * 1024 + i] = (float)bq;
      tb[tc * 1024 + 512 + i] = (float)cq;
    }
  }
}

// ---- layernorm (row=2048), writes bf16 ----
__global__ __launch_bounds__(256) void ln_kernel(const float* __restrict__ x,
                                                 const float* __restrict__ w,
                                                 const float* __restrict__ b,
                                                 u16* __restrict__ out,
                                                 const float* __restrict__ tb) {
  int row = blockIdx.x, tid = threadIdx.x;
  const float4* xr = (const float4*)(x + (size_t)row * 2048);
  float4 v0 = xr[tid], v1 = xr[tid + 256];
  float s = ((v0.x + v0.y) + (v0.z + v0.w)) + ((v1.x + v1.y) + (v1.z + v1.w));
#pragma unroll
  for (int m = 32; m; m >>= 1) s += __shfl_xor(s, m, 64);
  __shared__ float red1[4], red2[4];
  int wv = tid >> 6;
  if ((tid & 63) == 0) red1[wv] = s;
  __syncthreads();
  float mu = (red1[0] + red1[1] + red1[2] + red1[3]) * (1.0f / 2048.0f);
  float a0 = v0.x - mu, a1 = v0.y - mu, a2 = v0.z - mu, a3 = v0.w - mu;
  float a4 = v1.x - mu, a5 = v1.y - mu, a6 = v1.z - mu, a7 = v1.w - mu;
  float q = ((a0 * a0 + a1 * a1) + (a2 * a2 + a3 * a3)) +
            ((a4 * a4 + a5 * a5) + (a6 * a6 + a7 * a7));
#pragma unroll
  for (int m = 32; m; m >>= 1) q += __shfl_xor(q, m, 64);
  if ((tid & 63) == 0) red2[wv] = q;
  __syncthreads();
  float var = (red2[0] + red2[1] + red2[2] + red2[3]) * (1.0f / 2048.0f);
  float istd = pwl_log(var + 1e-5f, 1e-6f, 100.0f, -13.8155106f, 27.7405655f, tb + 3072, tb + 3584);
  const float4* wr4 = (const float4*)w;
  const float4* br4 = (const float4*)b;
  float4 w0 = wr4[tid], w1 = wr4[tid + 256];
  float4 b0 = br4[tid], b1 = br4[tid + 256];
  u16 o0 = f2bf(fmaf(a0 * istd, w0.x, b0.x));
  u16 o1 = f2bf(fmaf(a1 * istd, w0.y, b0.y));
  u16 o2 = f2bf(fmaf(a2 * istd, w0.z, b0.z));
  u16 o3 = f2bf(fmaf(a3 * istd, w0.w, b0.w));
  u16 o4 = f2bf(fmaf(a4 * istd, w1.x, b1.x));
  u16 o5 = f2bf(fmaf(a5 * istd, w1.y, b1.y));
  u16 o6 = f2bf(fmaf(a6 * istd, w1.z, b1.z));
  u16 o7 = f2bf(fmaf(a7 * istd, w1.w, b1.w));
  uint2 p0, p1;
  p0.x = (unsigned)o0 | ((unsigned)o1 << 16);
  p0.y = (unsigned)o2 | ((unsigned)o3 << 16);
  p1.x = (unsigned)o4 | ((unsigned)o5 << 16);
  p1.y = (unsigned)o6 | ((unsigned)o7 << 16);
  uint2* orow = (uint2*)(out + (size_t)row * 2048);
  orow[tid] = p0;
  orow[tid + 256] = p1;
}

// ---- fp32 [K][N] -> bf16 transposed [N][K] ----
__global__ __launch_bounds__(256) void cast_transpose(const float* __restrict__ W,
                                                      u16* __restrict__ WT, int K, int N) {
  __shared__ u16 s[64][130];
  int j0 = blockIdx.x * 64, i0 = blockIdx.y * 128;
  int tid = threadIdx.x;
  int c = tid & 63, g = tid >> 6;
#pragma unroll
  for (int rr = g; rr < 128; rr += 4) {
    s[c][rr] = f2bf(W[(size_t)(i0 + rr) * N + j0 + c]);
  }
  __syncthreads();
  int r = tid >> 2;
  int cc0 = (tid & 3) * 32;
  unsigned* dst = (unsigned*)(WT + (size_t)(j0 + r) * K + i0 + cc0);
#pragma unroll
  for (int ii = 0; ii < 16; ++ii) {
    unsigned lo = s[r][cc0 + 2 * ii], hi = s[r][cc0 + 2 * ii + 1];
    dst[ii] = lo | (hi << 16);
  }
}

// ---- V [t][d] (inside qkv) -> VT [bh][d][t] bf16, 64x64 tiles ----
__global__ __launch_bounds__(256) void vtrans_kernel(const u16* __restrict__ qkv,
                                                     u16* __restrict__ vt) {
  int tt = blockIdx.x, dd = blockIdx.y, bh = blockIdx.z;
  int b = bh >> 4, h = bh & 15;
  __shared__ u16 s[64][72];
  int tid = threadIdx.x;
  const u16* src = qkv + ((size_t)b * 1024 + tt * 64) * 6144 + 4096 + h * 128 + dd * 64;
#pragma unroll
  for (int it = 0; it < 2; ++it) {
    int idx = it * 256 + tid;
    int r = idx >> 3, c = idx & 7;
    u16x8 v = *(const u16x8*)(src + (size_t)r * 6144 + c * 8);
#pragma unroll
    for (int j = 0; j < 8; ++j) s[r][c * 8 + j] = v[j];
  }
  __syncthreads();
  u16* dst = vt + ((size_t)bh * 128 + dd * 64) * 1024 + tt * 64;
#pragma unroll
  for (int it = 0; it < 2; ++it) {
    int idx = it * 256 + tid;
    int d = idx >> 3, c2 = idx & 7;
    u16x8 o;
#pragma unroll
    for (int j = 0; j < 8; ++j) o[j] = s[c2 * 8 + j][d];
    *(u16x8*)(dst + (size_t)d * 1024 + c2 * 8) = o;
  }
}

// ---- 128x128 bf16 GEMM (m97 structure, 4 waves) — for large grids ----
template <int EPI>
__global__ __launch_bounds__(256) void gemm_bt(const u16* __restrict__ A,
                                               const u16* __restrict__ BT,
                                               const float* __restrict__ bias,
                                               const float* __restrict__ add,
                                               float* __restrict__ outF,
                                               u16* __restrict__ outH, int M, int N, int K,
                                               const float* __restrict__ tb) {
  __shared__ u16 sA[128 * 32], sB[128 * 32];
  int tid = threadIdx.x, lane = tid & 63, w = tid >> 6;
  int l15 = lane & 15, lg = lane >> 4;
  int wr = w >> 1, wc = w & 1;
  int mBase = blockIdx.y * 128, nBase = blockIdx.x * 128;

  f32x4 acc[4][4] = {};

  int rowA = tid >> 2, chA = tid & 3;
  const u16* gA = A + (size_t)(mBase + rowA) * K + chA * 8;
  const u16* gB = BT + (size_t)(nBase + rowA) * K + chA * 8;
  u16* sAw = sA + w * 512;
  u16* sAw2 = sA + 2048 + w * 512;
  u16* sBw = sB + w * 512;
  u16* sBw2 = sB + 2048 + w * 512;
  size_t k64 = (size_t)64 * K;

  for (int k0 = 0; k0 < K; k0 += 32) {
    gload_lds16(gA + k0, sAw);
    gload_lds16(gA + k0 + k64, sAw2);
    gload_lds16(gB + k0, sBw);
    gload_lds16(gB + k0 + k64, sBw2);
    __syncthreads();
    bf16x8 aF[4], bF[4];
#pragma unroll
    for (int m = 0; m < 4; ++m)
      aF[m] = *(const bf16x8*)&sA[(wr * 64 + m * 16 + l15) * 32 + lg * 8];
#pragma unroll
    for (int n = 0; n < 4; ++n)
      bF[n] = *(const bf16x8*)&sB[(wc * 64 + n * 16 + l15) * 32 + lg * 8];
#pragma unroll
    for (int m = 0; m < 4; ++m)
#pragma unroll
      for (int n = 0; n < 4; ++n) acc[m][n] = MFMA16(aF[m], bF[n], acc[m][n]);
    __syncthreads();
  }

  float bv[4];
#pragma unroll
  for (int n = 0; n < 4; ++n) bv[n] = bias[nBase + wc * 64 + n * 16 + l15];
#pragma unroll
  for (int m = 0; m < 4; ++m) {
    int row0 = mBase + wr * 64 + m * 16 + lg * 4;
#pragma unroll
    for (int n = 0; n < 4; ++n) {
      int col = nBase + wc * 64 + n * 16 + l15;
#pragma unroll
      for (int r = 0; r < 4; ++r) {
        size_t oidx = (size_t)(row0 + r) * N + col;
        float v = acc[m][n][r] + bv[n];
        if (EPI == 1) {
          v += add[oidx];
          outF[oidx] = v;
        } else if (EPI == 2) {
          v = pwl_lin(v, -10.0f, 10.0f, 511.0f / 20.0f, tb, tb + 512);
          outH[oidx] = f2bf(v);
        } else {
          outH[oidx] = f2bf(v);
        }
      }
    }
  }
}

// ---- 128x128 split-K GEMM, 8 waves, DOUBLE-BUFFERED 2-phase pipeline (T3 recipe).
// Per K-half group: dbuf LDS; stage tile t+1 BEFORE compute of tile t; one raw
// s_barrier + vmcnt(0) per K-step (no __syncthreads full drain in the loop).
template <int EPI>
__global__ __launch_bounds__(512) void gemm_bt_sk(const u16* __restrict__ A,
                                                  const u16* __restrict__ BT,
                                                  const float* __restrict__ bias,
                                                  const float* __restrict__ add,
                                                  float* __restrict__ outF,
                                                  u16* __restrict__ outH, int M, int N, int K,
                                                  const float* __restrict__ tb) {
  __shared__ u16 smem[32768];  // 64KB: [grp][buf][A 4096 | B 4096] u16
  float* red = (float*)smem;   // epilogue reuse

  int tid = threadIdx.x, lane = tid & 63, w = tid >> 6;
  int l15 = lane & 15, lg = lane >> 4;
  int q = w & 3, grp = w >> 2;  // quadrant within group, K-half group
  int wr = q >> 1, wc = q & 1;
  int mBase = blockIdx.y * 128, nBase = blockIdx.x * 128;
  int Kh = K >> 1;
  int NT = Kh >> 5;  // 32-wide K tiles per group

  f32x4 acc[4][4] = {};

  int ts = tid & 255;
  int rowA = ts >> 2, chA = ts & 3;
  const u16* gA = A + (size_t)(mBase + rowA) * K + (size_t)grp * Kh + chA * 8;
  const u16* gB = BT + (size_t)(nBase + rowA) * K + (size_t)grp * Kh + chA * 8;
  size_t k64 = (size_t)64 * K;
  int w4 = w & 3;

  u16* base = smem + grp * 16384;
  // stage dst (wave-linear) and read base per buffer
  u16* sAw[2] = {base + w4 * 512, base + 8192 + w4 * 512};
  u16* sBw[2] = {base + 4096 + w4 * 512, base + 8192 + 4096 + w4 * 512};
  const u16* sAr[2] = {base, base + 8192};
  const u16* sBr[2] = {base + 4096, base + 8192 + 4096};

#define STAGE_SK(c, k0)                          \
  {                                              \
    gload_lds16(gA + (k0), sAw[c]);              \
    gload_lds16(gA + (k0) + k64, sAw[c] + 2048); \
    gload_lds16(gB + (k0), sBw[c]);              \
    gload_lds16(gB + (k0) + k64, sBw[c] + 2048); \
  }

  // prologue: stage tile 0
  STAGE_SK(0, 0);
  asm volatile("s_waitcnt vmcnt(0)" ::: "memory");
  __builtin_amdgcn_s_barrier();

  int cur = 0;
  for (int t = 0; t < NT; ++t) {
    if (t + 1 < NT) STAGE_SK(cur ^ 1, (t + 1) * 32);
    bf16x8 aF[4], bF[4];
#pragma unroll
    for (int m = 0; m < 4; ++m)
      aF[m] = *(const bf16x8*)&sAr[cur][(wr * 64 + m * 16 + l15) * 32 + lg * 8];
#pragma unroll
    for (int n = 0; n < 4; ++n)
      bF[n] = *(const bf16x8*)&sBr[cur][(wc * 64 + n * 16 + l15) * 32 + lg * 8];
    __builtin_amdgcn_s_setprio(1);
#pragma unroll
    for (int m = 0; m < 4; ++m)
#pragma unroll
      for (int n = 0; n < 4; ++n) acc[m][n] = MFMA16(aF[m], bF[n], acc[m][n]);
    __builtin_amdgcn_s_setprio(0);
    asm volatile("s_waitcnt vmcnt(0)" ::: "memory");
    __builtin_amdgcn_s_barrier();
    cur ^= 1;
  }

  float bv[4];
#pragma unroll
  for (int n = 0; n < 4; ++n) bv[n] = bias[nBase + wc * 64 + n * 16 + l15];

  // merge grp1 partials into grp0 via LDS, 2 chunks of 2 m-rows
#pragma unroll
  for (int chunk = 0; chunk < 2; ++chunk) {
    if (grp == 1) {
#pragma unroll
      for (int mm = 0; mm < 2; ++mm)
#pragma unroll
        for (int n = 0; n < 4; ++n)
          *(f32x4*)(red + ((q * 8 + mm * 4 + n) << 8) + lane * 4) = acc[chunk * 2 + mm][n];
    }
    __syncthreads();
    if (grp == 0) {
#pragma unroll
      for (int mm = 0; mm < 2; ++mm) {
        int m = chunk * 2 + mm;
        int row0 = mBase + wr * 64 + m * 16 + lg * 4;
#pragma unroll
        for (int n = 0; n < 4; ++n) {
          f32x4 o = *(const f32x4*)(red + ((q * 8 + mm * 4 + n) << 8) + lane * 4);
          f32x4 a = acc[m][n];
          int col = nBase + wc * 64 + n * 16 + l15;
#pragma unroll
          for (int r = 0; r < 4; ++r) {
            size_t oidx = (size_t)(row0 + r) * N + col;
            float v = a[r] + o[r] + bv[n];
            if (EPI == 1) {
              v += add[oidx];
              outF[oidx] = v;
            } else if (EPI == 2) {
              v = pwl_lin(v, -10.0f, 10.0f, 511.0f / 20.0f, tb, tb + 512);
              outH[oidx] = f2bf(v);
            } else {
              outH[oidx] = f2bf(v);
            }
          }
        }
      }
    }
    __syncthreads();
  }
#undef STAGE_SK
}

// ---- flash attention: 1 block = 64 q rows of one (b,h); 4 waves x 16 q rows. ----
__global__ __launch_bounds__(256) void attn_kernel(const u16* __restrict__ qkv,
                                                   const u16* __restrict__ vt,
                                                   u16* __restrict__ outA,
                                                   const float* __restrict__ tb) {
  int bid = blockIdx.x;
  int qt = 15 - (bid >> 5);  // heavy diagonal blocks first
  int bh = bid & 31;
  int b = bh >> 4, h = bh & 15;
  int tid = threadIdx.x, lane = tid & 63, w = tid >> 6;
  int l15 = lane & 15, lg = lane >> 4;

  __shared__ u16 sQ[64 * 128];
  __shared__ u16 sK[64 * 128];
  __shared__ u16 sVT[128 * 64];
  __shared__ __bf16 sP[4][16 * 72];

  const size_t RS = 6144;
  int q0 = qt * 64;
  const u16* qg = qkv + ((size_t)b * 1024 + q0) * RS + h * 128;
  const u16* kg = qkv + (size_t)b * 1024 * RS + 2048 + h * 128;
  const u16* vg = vt + (size_t)bh * 128 * 1024;
  int ntiles = qt + 1;
  const float scale = 0.08838834764831845f;  // 1/sqrt(128)
  const float* EB = tb + 1024;
  const float* EC = tb + 1536;

#pragma unroll
  for (int it = 0; it < 4; ++it) {
    int idx = it * 256 + tid;
    int r = idx >> 4, ch = idx & 15;
    gload_lds16(qg + (size_t)r * RS + (ch ^ (r & 7)) * 8, sQ + (size_t)(it * 256 + w * 64) * 8);
  }
  __syncthreads();

  bf16x8 aQ[4];
#pragma unroll
  for (int kk = 0; kk < 4; ++kk) {
    int row = w * 16 + l15;
    int off = (row * 256 + ((kk * 64 + lg * 16) ^ ((row & 7) << 4))) >> 1;
    aQ[kk] = *(const bf16x8*)&sQ[off];
  }

  float mrun[4], ssum[4];
#pragma unroll
  for (int r = 0; r < 4; ++r) {
    mrun[r] = -3.0e38f;
    ssum[r] = 0.f;
  }
  f32x4 oacc[8] = {};
  int qrow_w = q0 + w * 16;

  for (int t = 0; t < ntiles; ++t) {
    __syncthreads();
#pragma unroll
    for (int it = 0; it < 4; ++it) {
      int idx = it * 256 + tid;
      int r = idx >> 4, ch = idx & 15;
      gload_lds16(kg + (size_t)(t * 64 + r) * RS + (ch ^ (r & 7)) * 8,
                  sK + (size_t)(it * 256 + w * 64) * 8);
      int d = idx >> 3, c = idx & 7;
      gload_lds16(vg + (size_t)d * 1024 + t * 64 + (c ^ (d & 7)) * 8,
                  sVT + (size_t)(it * 256 + w * 64) * 8);
    }
    __syncthreads();

    f32x4 sc[4];
#pragma unroll
    for (int n = 0; n < 4; ++n) {
      sc[n] = (f32x4){0.f, 0.f, 0.f, 0.f};
#pragma unroll
      for (int kk = 0; kk < 4; ++kk) {
        int row = n * 16 + l15;
        int off = (row * 256 + ((kk * 64 + lg * 16) ^ ((row & 7) << 4))) >> 1;
        bf16x8 bK = *(const bf16x8*)&sK[off];
        sc[n] = MFMA16(aQ[kk], bK, sc[n]);
      }
    }

    float mt[4], sv[4][4];
#pragma unroll
    for (int r = 0; r < 4; ++r) mt[r] = -3.0e38f;
#pragma unroll
    for (int n = 0; n < 4; ++n)
#pragma unroll
      for (int r = 0; r < 4; ++r) {
        int key = t * 64 + n * 16 + l15;
        int qq = qrow_w + lg * 4 + r;
        float v = (key <= qq) ? sc[n][r] * scale : -3.0e38f;
        sv[n][r] = v;
        mt[r] = fmaxf(mt[r], v);
      }
#pragma unroll
    for (int m = 8; m; m >>= 1)
#pragma unroll
      for (int r = 0; r < 4; ++r) mt[r] = fmaxf(mt[r], __shfl_xor(mt[r], m, 64));

#pragma unroll
    for (int r = 0; r < 4; ++r) {
      float mn = fmaxf(mrun[r], mt[r]);
      float f = __expf(mrun[r] - mn);
      mrun[r] = mn;
      ssum[r] *= f;
#pragma unroll
      for (int fi = 0; fi < 8; ++fi) oacc[fi][r] *= f;
    }

#pragma unroll
    for (int n = 0; n < 4; ++n)
#pragma unroll
      for (int r = 0; r < 4; ++r) {
        float scv = fminf(fmaxf(sv[n][r] - mrun[r], -30.0f), 0.0f);
        float e = pwl_lin(scv, -30.0f, 0.0f, 511.0f / 30.0f, EB, EC);
        ssum[r] += e;
        sP[w][(lg * 4 + r) * 72 + n * 16 + l15] = (__bf16)e;
      }

#pragma unroll
    for (int kk = 0; kk < 2; ++kk) {
      bf16x8 aP = *(const bf16x8*)&sP[w][l15 * 72 + kk * 32 + lg * 8];
#pragma unroll
      for (int fi = 0; fi < 8; ++fi) {
        int d = fi * 16 + l15;
        int off = (d * 128 + ((kk * 64 + lg * 16) ^ ((d & 7) << 4))) >> 1;
        bf16x8 bV = *(const bf16x8*)&sVT[off];
        oacc[fi] = MFMA16(aP, bV, oacc[fi]);
      }
    }
  }

#pragma unroll
  for (int m = 8; m; m >>= 1)
#pragma unroll
    for (int r = 0; r < 4; ++r) ssum[r] += __shfl_xor(ssum[r], m, 64);

  int skipped = 1024 - ntiles * 64;
#pragma unroll
  for (int r = 0; r < 4; ++r) {
    float s = ssum[r] + (float)skipped * 9.357623e-14f;
    float inv = pwl_log(s, 1e-3f, 4096.0f, -6.9077553f, 33.5620689f, tb + 2048, tb + 2560);
    int qq = qrow_w + lg * 4 + r;
    size_t base = ((size_t)b * 1024 + qq) * 2048 + (size_t)h * 128;
#pragma unroll
    for (int fi = 0; fi < 8; ++fi) outA[base + fi * 16 + l15] = f2bf(oacc[fi][r] * inv);
  }
}

extern "C" void kernel_launch(void* const* d_in, const int* in_sizes, int n_in, void* d_out,
                              int out_size, void* d_ws, size_t ws_size, hipStream_t stream) {
  const float* x = (const float*)d_in[0];
  const float* ln1w = (const float*)d_in[1];
  const float* ln1b = (const float*)d_in[2];
  const float* ln2w = (const float*)d_in[3];
  const float* ln2b = (const float*)d_in[4];
  const float* attnW = (const float*)d_in[5];
  const float* attnB = (const float*)d_in[6];
  const float* projW = (const float*)d_in[7];
  const float* projB = (const float*)d_in[8];
  const float* fcW = (const float*)d_in[9];
  const float* fcB = (const float*)d_in[10];
  const float* proj2W = (const float*)d_in[11];
  const float* proj2B = (const float*)d_in[12];
  float* out = (float*)d_out;

  char* ws = (char*)d_ws;
  float* tb = (float*)ws;                                            // 16 KB tables
  u16* WT = (u16*)(ws + 16384);                                      // 33.5 MB weight bf16^T
  u16* VT = WT;                                                      // aliases WT (free between qkv-GEMM and proj cast)
  u16* ABUF = (u16*)(ws + 16384 + 33554432);                         // 8.4 MB  ln1 / attn_out / ln2
  u16* QBUF = (u16*)(ws + 16384 + 33554432 + 8388608);               // 33.5 MB qkv / h
  float* X1 = (float*)(ws + 16384 + 33554432 + 8388608 + 33554432);  // 16.8 MB residual

  init_tables<<<1, 512, 0, stream>>>(tb);

  // x -> ln1 (bf16)
  ln_kernel<<<2048, 256, 0, stream>>>(x, ln1w, ln1b, ABUF, tb);
  // qkv = ln1 @ c_attn_w + b  (bf16 out)
  cast_transpose<<<dim3(6144 / 64, 2048 / 128), 256, 0, stream>>>(attnW, WT, 2048, 6144);
  gemm_bt<0><<<dim3(48, 16), 256, 0, stream>>>(ABUF, WT, attnB, nullptr, nullptr, QBUF, 2048,
                                               6144, 2048, tb);
  // V -> VT (bf16, [bh][d][t])
  vtrans_kernel<<<dim3(16, 2, 32), 256, 0, stream>>>(QBUF, VT);
  // attention -> ABUF (bf16, [B*T, D])
  attn_kernel<<<512, 256, 0, stream>>>(QBUF, VT, ABUF, tb);
  // x1 = x + attn @ c_proj_w + b  (f32)  [split-K 8-wave pipelined]
  cast_transpose<<<dim3(2048 / 64, 2048 / 128), 256, 0, stream>>>(projW, WT, 2048, 2048);
  gemm_bt_sk<1><<<dim3(16, 16), 512, 0, stream>>>(ABUF, WT, projB, x, X1, nullptr, 2048, 2048,
                                                  2048, tb);
  // ln2
  ln_kernel<<<2048, 256, 0, stream>>>(X1, ln2w, ln2b, ABUF, tb);
  // h = gelu(ln2 @ fc_w + b) (bf16)
  cast_transpose<<<dim3(8192 / 64, 2048 / 128), 256, 0, stream>>>(fcW, WT, 2048, 8192);
  gemm_bt<2><<<dim3(64, 16), 256, 0, stream>>>(ABUF, WT, fcB, nullptr, nullptr, QBUF, 2048,
                                               8192, 2048, tb);
  // out = x1 + h @ proj_w + b (f32)  [split-K 8-wave pipelined]
  cast_transpose<<<dim3(2048 / 64, 8192 / 128), 256, 0, stream>>>(proj2W, WT, 8192, 2048);
  gemm_bt_sk<1><<<dim3(16, 16), 512, 0, stream>>>(QBUF, WT, proj2B, X1, out, nullptr, 2048,
                                                  2048, 8192, tb);
}

// Round 6
// 690.020 us; speedup vs baseline: 1.0318x; 1.0318x over previous
//
#include <hip/hip_runtime.h>
#include <hip/hip_bf16.h>
#include <stdint.h>

typedef unsigned short u16;
typedef __bf16 bf16x8 __attribute__((ext_vector_type(8)));
typedef float f32x4 __attribute__((ext_vector_type(4)));
typedef u16 u16x8 __attribute__((ext_vector_type(8)));

#define MFMA16(a, b, c) __builtin_amdgcn_mfma_f32_16x16x32_bf16(a, b, c, 0, 0, 0)

typedef __attribute__((address_space(3))) unsigned as3_uint;
typedef __attribute__((address_space(1))) unsigned as1_uint;

__device__ __forceinline__ void gload_lds16(const void* g, void* l) {
  __builtin_amdgcn_global_load_lds((const as1_uint*)g, (as3_uint*)l, 16, 0, 0);
}

__device__ __forceinline__ u16 f2bf(float f) {
  unsigned u = __float_as_uint(f);
  u += 0x7FFF + ((u >> 16) & 1);
  return (u16)(u >> 16);
}

// y = b[i]*clamp(x) + c[i], uniform grid
__device__ __forceinline__ float pwl_lin(float x, float x0, float x1, float invStep,
                                         const float* __restrict__ Bt,
                                         const float* __restrict__ Ct) {
  float xc = fminf(fmaxf(x, x0), x1);
  int i = (int)floorf((x - x0) * invStep);
  i = max(0, min(510, i));
  return fmaf(Bt[i], xc, Ct[i]);
}

// geometric grid: index via log
__device__ __forceinline__ float pwl_log(float x, float x0, float x1, float lnx0, float invL,
                                         const float* __restrict__ Bt,
                                         const float* __restrict__ Ct) {
  float xc = fminf(fmaxf(x, x0), x1);
  int i = (int)floorf((logf(xc) - lnx0) * invL);
  i = max(0, min(510, i));
  return fmaf(Bt[i], xc, Ct[i]);
}

// ---- table init: (b,c) per segment for gelu/exp/inv/rsqrt, numpy-matched ----
__global__ void init_tables(float* __restrict__ tb) {
  __shared__ float xs[4][512], ys[4][512];
  int i = threadIdx.x;
  if (i < 512) {
    double t = (double)i / 511.0;
    float xg = (float)(-10.0 + 20.0 * t);
    double xd = (double)xg;
    xs[0][i] = xg;
    ys[0][i] = (float)(0.5 * xd * (1.0 + tanh(0.7978845608028654 * (xd + 0.044715 * xd * xd * xd))));
    float xe = (float)(-30.0 + 30.0 * t);
    xs[1][i] = xe;
    ys[1][i] = (float)exp((double)xe);
    double li = -3.0 + t * (log10(4096.0) + 3.0);
    float xi = (float)pow(10.0, li);
    if (i == 0) xi = 1e-3f;
    if (i == 511) xi = 4096.0f;
    xs[2][i] = xi;
    ys[2][i] = 1.0f / xi;
    double lr = -6.0 + t * 8.0;
    float xr2 = (float)pow(10.0, lr);
    if (i == 0) xr2 = 1e-6f;
    if (i == 511) xr2 = 100.0f;
    xs[3][i] = xr2;
    ys[3][i] = 1.0f / sqrtf(xr2);
  }
  __syncthreads();
  if (i < 511) {
#pragma unroll
    for (int tc = 0; tc < 4; ++tc) {
      double bq = ((double)ys[tc][i + 1] - (double)ys[tc][i]) /
                  ((double)xs[tc][i + 1] - (double)xs[tc][i]);
      double cq = (double)ys[tc][i] - bq * (double)xs[tc][i];
      tb[tc * 1024 + i] = (float)bq;
      tb[tc * 1024 + 512 + i] = (float)cq;
    }
  }
}

// ---- layernorm (row=2048), writes bf16 ----
__global__ __launch_bounds__(256) void ln_kernel(const float* __restrict__ x,
                                                 const float* __restrict__ w,
                                                 const float* __restrict__ b,
                                                 u16* __restrict__ out,
                                                 const float* __restrict__ tb) {
  int row = blockIdx.x, tid = threadIdx.x;
  const float4* xr = (const float4*)(x + (size_t)row * 2048);
  float4 v0 = xr[tid], v1 = xr[tid + 256];
  float s = ((v0.x + v0.y) + (v0.z + v0.w)) + ((v1.x + v1.y) + (v1.z + v1.w));
#pragma unroll
  for (int m = 32; m; m >>= 1) s += __shfl_xor(s, m, 64);
  __shared__ float red1[4], red2[4];
  int wv = tid >> 6;
  if ((tid & 63) == 0) red1[wv] = s;
  __syncthreads();
  float mu = (red1[0] + red1[1] + red1[2] + red1[3]) * (1.0f / 2048.0f);
  float a0 = v0.x - mu, a1 = v0.y - mu, a2 = v0.z - mu, a3 = v0.w - mu;
  float a4 = v1.x - mu, a5 = v1.y - mu, a6 = v1.z - mu, a7 = v1.w - mu;
  float q = ((a0 * a0 + a1 * a1) + (a2 * a2 + a3 * a3)) +
            ((a4 * a4 + a5 * a5) + (a6 * a6 + a7 * a7));
#pragma unroll
  for (int m = 32; m; m >>= 1) q += __shfl_xor(q, m, 64);
  if ((tid & 63) == 0) red2[wv] = q;
  __syncthreads();
  float var = (red2[0] + red2[1] + red2[2] + red2[3]) * (1.0f / 2048.0f);
  float istd = pwl_log(var + 1e-5f, 1e-6f, 100.0f, -13.8155106f, 27.7405655f, tb + 3072, tb + 3584);
  const float4* wr4 = (const float4*)w;
  const float4* br4 = (const float4*)b;
  float4 w0 = wr4[tid], w1 = wr4[tid + 256];
  float4 b0 = br4[tid], b1 = br4[tid + 256];
  u16 o0 = f2bf(fmaf(a0 * istd, w0.x, b0.x));
  u16 o1 = f2bf(fmaf(a1 * istd, w0.y, b0.y));
  u16 o2 = f2bf(fmaf(a2 * istd, w0.z, b0.z));
  u16 o3 = f2bf(fmaf(a3 * istd, w0.w, b0.w));
  u16 o4 = f2bf(fmaf(a4 * istd, w1.x, b1.x));
  u16 o5 = f2bf(fmaf(a5 * istd, w1.y, b1.y));
  u16 o6 = f2bf(fmaf(a6 * istd, w1.z, b1.z));
  u16 o7 = f2bf(fmaf(a7 * istd, w1.w, b1.w));
  uint2 p0, p1;
  p0.x = (unsigned)o0 | ((unsigned)o1 << 16);
  p0.y = (unsigned)o2 | ((unsigned)o3 << 16);
  p1.x = (unsigned)o4 | ((unsigned)o5 << 16);
  p1.y = (unsigned)o6 | ((unsigned)o7 << 16);
  uint2* orow = (uint2*)(out + (size_t)row * 2048);
  orow[tid] = p0;
  orow[tid + 256] = p1;
}

// ---- fp32 [K][N] -> bf16 transposed [N][K] ----
__global__ __launch_bounds__(256) void cast_transpose(const float* __restrict__ W,
                                                      u16* __restrict__ WT, int K, int N) {
  __shared__ u16 s[64][130];
  int j0 = blockIdx.x * 64, i0 = blockIdx.y * 128;
  int tid = threadIdx.x;
  int c = tid & 63, g = tid >> 6;
#pragma unroll
  for (int rr = g; rr < 128; rr += 4) {
    s[c][rr] = f2bf(W[(size_t)(i0 + rr) * N + j0 + c]);
  }
  __syncthreads();
  int r = tid >> 2;
  int cc0 = (tid & 3) * 32;
  unsigned* dst = (unsigned*)(WT + (size_t)(j0 + r) * K + i0 + cc0);
#pragma unroll
  for (int ii = 0; ii < 16; ++ii) {
    unsigned lo = s[r][cc0 + 2 * ii], hi = s[r][cc0 + 2 * ii + 1];
    dst[ii] = lo | (hi << 16);
  }
}

// ---- V [t][d] (inside qkv) -> VT [bh][d][t] bf16, 64x64 tiles ----
__global__ __launch_bounds__(256) void vtrans_kernel(const u16* __restrict__ qkv,
                                                     u16* __restrict__ vt) {
  int tt = blockIdx.x, dd = blockIdx.y, bh = blockIdx.z;
  int b = bh >> 4, h = bh & 15;
  __shared__ u16 s[64][72];
  int tid = threadIdx.x;
  const u16* src = qkv + ((size_t)b * 1024 + tt * 64) * 6144 + 4096 + h * 128 + dd * 64;
#pragma unroll
  for (int it = 0; it < 2; ++it) {
    int idx = it * 256 + tid;
    int r = idx >> 3, c = idx & 7;
    u16x8 v = *(const u16x8*)(src + (size_t)r * 6144 + c * 8);
#pragma unroll
    for (int j = 0; j < 8; ++j) s[r][c * 8 + j] = v[j];
  }
  __syncthreads();
  u16* dst = vt + ((size_t)bh * 128 + dd * 64) * 1024 + tt * 64;
#pragma unroll
  for (int it = 0; it < 2; ++it) {
    int idx = it * 256 + tid;
    int d = idx >> 3, c2 = idx & 7;
    u16x8 o;
#pragma unroll
    for (int j = 0; j < 8; ++j) o[j] = s[c2 * 8 + j][d];
    *(u16x8*)(dst + (size_t)d * 1024 + c2 * 8) = o;
  }
}

// ---- 128x128 bf16 GEMM (m97 structure, 4 waves) — for large grids ----
template <int EPI>
__global__ __launch_bounds__(256) void gemm_bt(const u16* __restrict__ A,
                                               const u16* __restrict__ BT,
                                               const float* __restrict__ bias,
                                               const float* __restrict__ add,
                                               float* __restrict__ outF,
                                               u16* __restrict__ outH, int M, int N, int K,
                                               const float* __restrict__ tb) {
  __shared__ u16 sA[128 * 32], sB[128 * 32];
  int tid = threadIdx.x, lane = tid & 63, w = tid >> 6;
  int l15 = lane & 15, lg = lane >> 4;
  int wr = w >> 1, wc = w & 1;
  int mBase = blockIdx.y * 128, nBase = blockIdx.x * 128;

  f32x4 acc[4][4] = {};

  int rowA = tid >> 2, chA = tid & 3;
  const u16* gA = A + (size_t)(mBase + rowA) * K + chA * 8;
  const u16* gB = BT + (size_t)(nBase + rowA) * K + chA * 8;
  u16* sAw = sA + w * 512;
  u16* sAw2 = sA + 2048 + w * 512;
  u16* sBw = sB + w * 512;
  u16* sBw2 = sB + 2048 + w * 512;
  size_t k64 = (size_t)64 * K;

  for (int k0 = 0; k0 < K; k0 += 32) {
    gload_lds16(gA + k0, sAw);
    gload_lds16(gA + k0 + k64, sAw2);
    gload_lds16(gB + k0, sBw);
    gload_lds16(gB + k0 + k64, sBw2);
    __syncthreads();
    bf16x8 aF[4], bF[4];
#pragma unroll
    for (int m = 0; m < 4; ++m)
      aF[m] = *(const bf16x8*)&sA[(wr * 64 + m * 16 + l15) * 32 + lg * 8];
#pragma unroll
    for (int n = 0; n < 4; ++n)
      bF[n] = *(const bf16x8*)&sB[(wc * 64 + n * 16 + l15) * 32 + lg * 8];
#pragma unroll
    for (int m = 0; m < 4; ++m)
#pragma unroll
      for (int n = 0; n < 4; ++n) acc[m][n] = MFMA16(aF[m], bF[n], acc[m][n]);
    __syncthreads();
  }

  float bv[4];
#pragma unroll
  for (int n = 0; n < 4; ++n) bv[n] = bias[nBase + wc * 64 + n * 16 + l15];
#pragma unroll
  for (int m = 0; m < 4; ++m) {
    int row0 = mBase + wr * 64 + m * 16 + lg * 4;
#pragma unroll
    for (int n = 0; n < 4; ++n) {
      int col = nBase + wc * 64 + n * 16 + l15;
#pragma unroll
      for (int r = 0; r < 4; ++r) {
        size_t oidx = (size_t)(row0 + r) * N + col;
        float v = acc[m][n][r] + bv[n];
        if (EPI == 1) {
          v += add[oidx];
          outF[oidx] = v;
        } else if (EPI == 2) {
          v = pwl_lin(v, -10.0f, 10.0f, 511.0f / 20.0f, tb, tb + 512);
          outH[oidx] = f2bf(v);
        } else {
          outH[oidx] = f2bf(v);
        }
      }
    }
  }
}

// ---- 64x128 bf16 GEMM (m97 structure, 4 waves = 2x2 of 32x64) — for small-grid
// shapes (M=N=2048): grid 32x16 = 512 blocks = 2 blocks/CU restores the implicit
// wave-level overlap (m114) that 1-block/CU grids lose at every barrier drain.
template <int EPI>
__global__ __launch_bounds__(256) void gemm_bt64(const u16* __restrict__ A,
                                                 const u16* __restrict__ BT,
                                                 const float* __restrict__ bias,
                                                 const float* __restrict__ add,
                                                 float* __restrict__ outF,
                                                 u16* __restrict__ outH, int M, int N, int K,
                                                 const float* __restrict__ tb) {
  __shared__ u16 sA[64 * 32], sB[128 * 32];
  int tid = threadIdx.x, lane = tid & 63, w = tid >> 6;
  int l15 = lane & 15, lg = lane >> 4;
  int wr = w >> 1, wc = w & 1;
  int mBase = blockIdx.y * 64, nBase = blockIdx.x * 128;

  f32x4 acc[2][4] = {};

  int rowA = tid >> 2, chA = tid & 3;  // rowA in [0,64)
  const u16* gA = A + (size_t)(mBase + rowA) * K + chA * 8;
  const u16* gB = BT + (size_t)(nBase + rowA) * K + chA * 8;
  u16* sAw = sA + w * 512;
  u16* sBw = sB + w * 512;
  u16* sBw2 = sB + 2048 + w * 512;
  size_t k64 = (size_t)64 * K;

  for (int k0 = 0; k0 < K; k0 += 32) {
    gload_lds16(gA + k0, sAw);
    gload_lds16(gB + k0, sBw);
    gload_lds16(gB + k0 + k64, sBw2);
    __syncthreads();
    bf16x8 aF[2], bF[4];
#pragma unroll
    for (int m = 0; m < 2; ++m)
      aF[m] = *(const bf16x8*)&sA[(wr * 32 + m * 16 + l15) * 32 + lg * 8];
#pragma unroll
    for (int n = 0; n < 4; ++n)
      bF[n] = *(const bf16x8*)&sB[(wc * 64 + n * 16 + l15) * 32 + lg * 8];
#pragma unroll
    for (int m = 0; m < 2; ++m)
#pragma unroll
      for (int n = 0; n < 4; ++n) acc[m][n] = MFMA16(aF[m], bF[n], acc[m][n]);
    __syncthreads();
  }

  float bv[4];
#pragma unroll
  for (int n = 0; n < 4; ++n) bv[n] = bias[nBase + wc * 64 + n * 16 + l15];
#pragma unroll
  for (int m = 0; m < 2; ++m) {
    int row0 = mBase + wr * 32 + m * 16 + lg * 4;
#pragma unroll
    for (int n = 0; n < 4; ++n) {
      int col = nBase + wc * 64 + n * 16 + l15;
#pragma unroll
      for (int r = 0; r < 4; ++r) {
        size_t oidx = (size_t)(row0 + r) * N + col;
        float v = acc[m][n][r] + bv[n];
        if (EPI == 1) {
          v += add[oidx];
          outF[oidx] = v;
        } else if (EPI == 2) {
          v = pwl_lin(v, -10.0f, 10.0f, 511.0f / 20.0f, tb, tb + 512);
          outH[oidx] = f2bf(v);
        } else {
          outH[oidx] = f2bf(v);
        }
      }
    }
  }
}

// ---- flash attention: 1 block = 64 q rows of one (b,h); 4 waves x 16 q rows. ----
__global__ __launch_bounds__(256) void attn_kernel(const u16* __restrict__ qkv,
                                                   const u16* __restrict__ vt,
                                                   u16* __restrict__ outA,
                                                   const float* __restrict__ tb) {
  int bid = blockIdx.x;
  int qt = 15 - (bid >> 5);  // heavy diagonal blocks first
  int bh = bid & 31;
  int b = bh >> 4, h = bh & 15;
  int tid = threadIdx.x, lane = tid & 63, w = tid >> 6;
  int l15 = lane & 15, lg = lane >> 4;

  __shared__ u16 sQ[64 * 128];
  __shared__ u16 sK[64 * 128];
  __shared__ u16 sVT[128 * 64];
  __shared__ __bf16 sP[4][16 * 72];

  const size_t RS = 6144;
  int q0 = qt * 64;
  const u16* qg = qkv + ((size_t)b * 1024 + q0) * RS + h * 128;
  const u16* kg = qkv + (size_t)b * 1024 * RS + 2048 + h * 128;
  const u16* vg = vt + (size_t)bh * 128 * 1024;
  int ntiles = qt + 1;
  const float scale = 0.08838834764831845f;  // 1/sqrt(128)
  const float* EB = tb + 1024;
  const float* EC = tb + 1536;

#pragma unroll
  for (int it = 0; it < 4; ++it) {
    int idx = it * 256 + tid;
    int r = idx >> 4, ch = idx & 15;
    gload_lds16(qg + (size_t)r * RS + (ch ^ (r & 7)) * 8, sQ + (size_t)(it * 256 + w * 64) * 8);
  }
  __syncthreads();

  bf16x8 aQ[4];
#pragma unroll
  for (int kk = 0; kk < 4; ++kk) {
    int row = w * 16 + l15;
    int off = (row * 256 + ((kk * 64 + lg * 16) ^ ((row & 7) << 4))) >> 1;
    aQ[kk] = *(const bf16x8*)&sQ[off];
  }

  float mrun[4], ssum[4];
#pragma unroll
  for (int r = 0; r < 4; ++r) {
    mrun[r] = -3.0e38f;
    ssum[r] = 0.f;
  }
  f32x4 oacc[8] = {};
  int qrow_w = q0 + w * 16;

  for (int t = 0; t < ntiles; ++t) {
    __syncthreads();
#pragma unroll
    for (int it = 0; it < 4; ++it) {
      int idx = it * 256 + tid;
      int r = idx >> 4, ch = idx & 15;
      gload_lds16(kg + (size_t)(t * 64 + r) * RS + (ch ^ (r & 7)) * 8,
                  sK + (size_t)(it * 256 + w * 64) * 8);
      int d = idx >> 3, c = idx & 7;
      gload_lds16(vg + (size_t)d * 1024 + t * 64 + (c ^ (d & 7)) * 8,
                  sVT + (size_t)(it * 256 + w * 64) * 8);
    }
    __syncthreads();

    f32x4 sc[4];
#pragma unroll
    for (int n = 0; n < 4; ++n) {
      sc[n] = (f32x4){0.f, 0.f, 0.f, 0.f};
#pragma unroll
      for (int kk = 0; kk < 4; ++kk) {
        int row = n * 16 + l15;
        int off = (row * 256 + ((kk * 64 + lg * 16) ^ ((row & 7) << 4))) >> 1;
        bf16x8 bK = *(const bf16x8*)&sK[off];
        sc[n] = MFMA16(aQ[kk], bK, sc[n]);
      }
    }

    float mt[4], sv[4][4];
#pragma unroll
    for (int r = 0; r < 4; ++r) mt[r] = -3.0e38f;
#pragma unroll
    for (int n = 0; n < 4; ++n)
#pragma unroll
      for (int r = 0; r < 4; ++r) {
        int key = t * 64 + n * 16 + l15;
        int qq = qrow_w + lg * 4 + r;
        float v = (key <= qq) ? sc[n][r] * scale : -3.0e38f;
        sv[n][r] = v;
        mt[r] = fmaxf(mt[r], v);
      }
#pragma unroll
    for (int m = 8; m; m >>= 1)
#pragma unroll
      for (int r = 0; r < 4; ++r) mt[r] = fmaxf(mt[r], __shfl_xor(mt[r], m, 64));

#pragma unroll
    for (int r = 0; r < 4; ++r) {
      float mn = fmaxf(mrun[r], mt[r]);
      float f = __expf(mrun[r] - mn);
      mrun[r] = mn;
      ssum[r] *= f;
#pragma unroll
      for (int fi = 0; fi < 8; ++fi) oacc[fi][r] *= f;
    }

#pragma unroll
    for (int n = 0; n < 4; ++n)
#pragma unroll
      for (int r = 0; r < 4; ++r) {
        float scv = fminf(fmaxf(sv[n][r] - mrun[r], -30.0f), 0.0f);
        float e = pwl_lin(scv, -30.0f, 0.0f, 511.0f / 30.0f, EB, EC);
        ssum[r] += e;
        sP[w][(lg * 4 + r) * 72 + n * 16 + l15] = (__bf16)e;
      }

#pragma unroll
    for (int kk = 0; kk < 2; ++kk) {
      bf16x8 aP = *(const bf16x8*)&sP[w][l15 * 72 + kk * 32 + lg * 8];
#pragma unroll
      for (int fi = 0; fi < 8; ++fi) {
        int d = fi * 16 + l15;
        int off = (d * 128 + ((kk * 64 + lg * 16) ^ ((d & 7) << 4))) >> 1;
        bf16x8 bV = *(const bf16x8*)&sVT[off];
        oacc[fi] = MFMA16(aP, bV, oacc[fi]);
      }
    }
  }

#pragma unroll
  for (int m = 8; m; m >>= 1)
#pragma unroll
    for (int r = 0; r < 4; ++r) ssum[r] += __shfl_xor(ssum[r], m, 64);

  int skipped = 1024 - ntiles * 64;
#pragma unroll
  for (int r = 0; r < 4; ++r) {
    float s = ssum[r] + (float)skipped * 9.357623e-14f;
    float inv = pwl_log(s, 1e-3f, 4096.0f, -6.9077553f, 33.5620689f, tb + 2048, tb + 2560);
    int qq = qrow_w + lg * 4 + r;
    size_t base = ((size_t)b * 1024 + qq) * 2048 + (size_t)h * 128;
#pragma unroll
    for (int fi = 0; fi < 8; ++fi) outA[base + fi * 16 + l15] = f2bf(oacc[fi][r] * inv);
  }
}

extern "C" void kernel_launch(void* const* d_in, const int* in_sizes, int n_in, void* d_out,
                              int out_size, void* d_ws, size_t ws_size, hipStream_t stream) {
  const float* x = (const float*)d_in[0];
  const float* ln1w = (const float*)d_in[1];
  const float* ln1b = (const float*)d_in[2];
  const float* ln2w = (const float*)d_in[3];
  const float* ln2b = (const float*)d_in[4];
  const float* attnW = (const float*)d_in[5];
  const float* attnB = (const float*)d_in[6];
  const float* projW = (const float*)d_in[7];
  const float* projB = (const float*)d_in[8];
  const float* fcW = (const float*)d_in[9];
  const float* fcB = (const float*)d_in[10];
  const float* proj2W = (const float*)d_in[11];
  const float* proj2B = (const float*)d_in[12];
  float* out = (float*)d_out;

  char* ws = (char*)d_ws;
  float* tb = (float*)ws;                                            // 16 KB tables
  u16* WT = (u16*)(ws + 16384);                                      // 33.5 MB weight bf16^T
  u16* VT = WT;                                                      // aliases WT (free between qkv-GEMM and proj cast)
  u16* ABUF = (u16*)(ws + 16384 + 33554432);                         // 8.4 MB  ln1 / attn_out / ln2
  u16* QBUF = (u16*)(ws + 16384 + 33554432 + 8388608);               // 33.5 MB qkv / h
  float* X1 = (float*)(ws + 16384 + 33554432 + 8388608 + 33554432);  // 16.8 MB residual

  init_tables<<<1, 512, 0, stream>>>(tb);

  // x -> ln1 (bf16)
  ln_kernel<<<2048, 256, 0, stream>>>(x, ln1w, ln1b, ABUF, tb);
  // qkv = ln1 @ c_attn_w + b  (bf16 out)
  cast_transpose<<<dim3(6144 / 64, 2048 / 128), 256, 0, stream>>>(attnW, WT, 2048, 6144);
  gemm_bt<0><<<dim3(48, 16), 256, 0, stream>>>(ABUF, WT, attnB, nullptr, nullptr, QBUF, 2048,
                                               6144, 2048, tb);
  // V -> VT (bf16, [bh][d][t])
  vtrans_kernel<<<dim3(16, 2, 32), 256, 0, stream>>>(QBUF, VT);
  // attention -> ABUF (bf16, [B*T, D])
  attn_kernel<<<512, 256, 0, stream>>>(QBUF, VT, ABUF, tb);
  // x1 = x + attn @ c_proj_w + b  (f32)  [64x128 tile: 512 blocks = 2/CU]
  cast_transpose<<<dim3(2048 / 64, 2048 / 128), 256, 0, stream>>>(projW, WT, 2048, 2048);
  gemm_bt64<1><<<dim3(16, 32), 256, 0, stream>>>(ABUF, WT, projB, x, X1, nullptr, 2048, 2048,
                                                 2048, tb);
  // ln2
  ln_kernel<<<2048, 256, 0, stream>>>(X1, ln2w, ln2b, ABUF, tb);
  // h = gelu(ln2 @ fc_w + b) (bf16)
  cast_transpose<<<dim3(8192 / 64, 2048 / 128), 256, 0, stream>>>(fcW, WT, 2048, 8192);
  gemm_bt<2><<<dim3(64, 16), 256, 0, stream>>>(ABUF, WT, fcB, nullptr, nullptr, QBUF, 2048,
                                               8192, 2048, tb);
  // out = x1 + h @ proj_w + b (f32)  [64x128 tile: 512 blocks = 2/CU]
  cast_transpose<<<dim3(2048 / 64, 8192 / 128), 256, 0, stream>>>(proj2W, WT, 8192, 2048);
  gemm_bt64<1><<<dim3(16, 32), 256, 0, stream>>>(QBUF, WT, proj2B, X1, out, nullptr, 2048,
                                                 2048, 8192, tb);
}